// Round 1
// baseline (604.228 us; speedup 1.0000x reference)
//
#include <hip/hip_runtime.h>
#include <stdint.h>

// ---------- helpers ----------
typedef __attribute__((ext_vector_type(8))) short short8;   // 8 x bf16 (4 VGPRs)
typedef __attribute__((ext_vector_type(4))) float floatx4;  // MFMA accum

__device__ __forceinline__ unsigned short f2bf(float f) {
  union { float f; unsigned int u; } c; c.f = f;
  unsigned int u = c.u;
  unsigned int r = (u + 0x7fffu + ((u >> 16) & 1u)) >> 16;  // RNE
  return (unsigned short)r;
}

// async global->LDS, 16B per lane. LDS dest is wave-uniform base + lane*16.
__device__ __forceinline__ void load16_to_lds(const void* g, void* l) {
  __builtin_amdgcn_global_load_lds(
      (const __attribute__((address_space(1))) unsigned int*)g,
      (__attribute__((address_space(3))) unsigned int*)l, 16, 0, 0);
}

// ---------- elementwise kernels ----------
__global__ void f32_to_bf16_kernel(const float* __restrict__ in,
                                   unsigned short* __restrict__ out, long n4) {
  long i = blockIdx.x * (long)blockDim.x + threadIdx.x;
  if (i >= n4) return;
  float4 v = ((const float4*)in)[i];
  ushort4 o;
  o.x = f2bf(v.x); o.y = f2bf(v.y); o.z = f2bf(v.z); o.w = f2bf(v.w);
  ((ushort4*)out)[i] = o;
}

__global__ void dequant2_kernel(const float* __restrict__ w1q,
                                const float* __restrict__ s1,
                                const float* __restrict__ w3q,
                                const float* __restrict__ s3,
                                unsigned short* __restrict__ o1,
                                unsigned short* __restrict__ o3,
                                int K, int sK) {
  int n = blockIdx.y;
  int k = blockIdx.x * 1024 + threadIdx.x * 4;
  size_t idx = (size_t)n * K + k;
  int sidx = (n >> 7) * sK + (k >> 7);
  float sc1 = s1[sidx], sc3 = s3[sidx];
  float4 v1 = *(const float4*)(w1q + idx);
  float4 v3 = *(const float4*)(w3q + idx);
  ushort4 a, b;
  a.x = f2bf(v1.x * sc1); a.y = f2bf(v1.y * sc1);
  a.z = f2bf(v1.z * sc1); a.w = f2bf(v1.w * sc1);
  b.x = f2bf(v3.x * sc3); b.y = f2bf(v3.y * sc3);
  b.z = f2bf(v3.z * sc3); b.w = f2bf(v3.w * sc3);
  *(ushort4*)(o1 + idx) = a;
  *(ushort4*)(o3 + idx) = b;
}

__global__ void dequant1_kernel(const float* __restrict__ wq,
                                const float* __restrict__ s,
                                unsigned short* __restrict__ out,
                                int K, int sK) {
  int n = blockIdx.y;
  int k = blockIdx.x * 1024 + threadIdx.x * 4;
  size_t idx = (size_t)n * K + k;
  float sc = s[(n >> 7) * sK + (k >> 7)];
  float4 v = *(const float4*)(wq + idx);
  ushort4 o;
  o.x = f2bf(v.x * sc); o.y = f2bf(v.y * sc);
  o.z = f2bf(v.z * sc); o.w = f2bf(v.w * sc);
  *(ushort4*)(out + idx) = o;
}

// ---------- 8-phase dual GEMM + silu ----------
// BM=256, BN=128, BK=64. 512 threads = 8 waves (4M x 2N), per-wave 64x64 dual.
// LDS: 2 x (A 32K + B1 16K + B3 16K) = 128 KiB -> 1 block/CU, 2 waves/SIMD.
// Phases per K-tile (16 MFMA each):
//   P1: read A.kh0+B1.kh0, stage b1(t+1), g-MFMA
//   P2: read A.kh1+B1.kh1, stage b3(t+1), g-MFMA, vmcnt(8)   <- B3(t) landed
//   P3: read B3.kh0,       stage a(t+2) c0/c1, u-MFMA        <- As[cb] free after P2
//   P4: read B3.kh1,       stage a(t+2) c2/c3, u-MFMA, vmcnt(6) <- A/B1(t+1) landed
// Per-wave VMEM queue (issue order b1,b3,a,a per tile) makes the counted
// waits exact; tail tiles keep issuing with clamped k so counts stay uniform
// (writes land only in dead regions).
#define SBAR()   __builtin_amdgcn_s_barrier()
#define SCHED0() __builtin_amdgcn_sched_barrier(0)

__global__ __launch_bounds__(512, 2) void dual_gemm_silu_8p(
    const unsigned short* __restrict__ A,   // [M,K] bf16 (x)
    const unsigned short* __restrict__ B1,  // [N,K] bf16 (w1)
    const unsigned short* __restrict__ B3,  // [N,K] bf16 (w3)
    unsigned short* __restrict__ C,         // [M,N] bf16 fused
    int M, int N, int K) {
  __shared__ unsigned short As[2][256 * 64];   // 64 KB
  __shared__ unsigned short B1s[2][128 * 64];  // 32 KB
  __shared__ unsigned short B3s[2][128 * 64];  // 32 KB

  const int tid = threadIdx.x;
  const int lane = tid & 63;
  const int wave = tid >> 6;      // 0..7
  const int wm = wave >> 1;       // 0..3  (M quarter, 64 rows)
  const int wn = wave & 1;        // 0..1  (N half, 64 cols)

  // XCD-aware bijective swizzle (nwg = 896, % 8 == 0)
  const int nwg = (int)gridDim.x;
  const int swz = ((int)blockIdx.x & 7) * (nwg >> 3) + ((int)blockIdx.x >> 3);
  const int NBN = N >> 7;         // 56 n-blocks
  const int bm = swz / NBN;
  const int bn = swz - bm * NBN;
  const int m0 = bm * 256, n0 = bn * 128;

  // staging map: unit u = tid + 512*c; row = u>>3; col-unit swizzled by row&7
  int soff[4], sdst[4];
#pragma unroll
  for (int p = 0; p < 4; p++) {
    int u = tid + 512 * p;
    int r = u >> 3;
    int c = ((u & 7) ^ (r & 7)) * 8;
    soff[p] = r * K + c;
    sdst[p] = u * 8;
  }

  const int q = lane >> 4;        // 0..3
  const int r16 = lane & 15;
  const int rx = r16 & 7;
  int arowE[4], browE[4];         // element base = row*64
#pragma unroll
  for (int i = 0; i < 4; i++) arowE[i] = (wm * 64 + i * 16 + r16) * 64;
#pragma unroll
  for (int j = 0; j < 4; j++) browE[j] = (wn * 64 + j * 16 + r16) * 64;
  const int kx0 = (q ^ rx) * 8;         // kh=0 swizzled kblk byte-elem offset
  const int kx1 = ((4 + q) ^ rx) * 8;   // kh=1

  floatx4 acc_g[4][4], acc_u[4][4];
#pragma unroll
  for (int i = 0; i < 4; i++)
#pragma unroll
    for (int j = 0; j < 4; j++) {
      acc_g[i][j] = (floatx4){0.f, 0.f, 0.f, 0.f};
      acc_u[i][j] = (floatx4){0.f, 0.f, 0.f, 0.f};
    }

  const unsigned short* Abase = A + (size_t)m0 * K;
  const unsigned short* B1base = B1 + (size_t)n0 * K;
  const unsigned short* B3base = B3 + (size_t)n0 * K;

  const int NT = K >> 6;   // 32

  // ---- prologue: a(0)x4, b1(0)x2, b3(0)x2, a(1)x4; wait oldest 6 ----
#pragma unroll
  for (int c = 0; c < 4; c++) load16_to_lds(Abase + soff[c], &As[0][sdst[c]]);
#pragma unroll
  for (int c = 0; c < 2; c++) load16_to_lds(B1base + soff[c], &B1s[0][sdst[c]]);
#pragma unroll
  for (int c = 0; c < 2; c++) load16_to_lds(B3base + soff[c], &B3s[0][sdst[c]]);
#pragma unroll
  for (int c = 0; c < 4; c++) load16_to_lds(Abase + soff[c] + 64, &As[1][sdst[c]]);
  asm volatile("s_waitcnt vmcnt(6)" ::: "memory");  // a(0),b1(0) landed
  SBAR();
  SCHED0();

  short8 a0[4], a1[4], bb[4];

  for (int t = 0; t < NT; ++t) {
    const int cb = t & 1, nb = cb ^ 1;
    const unsigned short* Ac = As[cb];
    const unsigned short* B1c = B1s[cb];
    const unsigned short* B3c = B3s[cb];
    const int k1 = (t + 1 < NT ? t + 1 : NT - 1) << 6;
    const int k2 = (t + 2 < NT ? t + 2 : NT - 1) << 6;

    // -------- P1 --------
#pragma unroll
    for (int i = 0; i < 4; i++) a0[i] = *(const short8*)&Ac[arowE[i] + kx0];
#pragma unroll
    for (int j = 0; j < 4; j++) bb[j] = *(const short8*)&B1c[browE[j] + kx0];
    load16_to_lds(B1base + soff[0] + k1, &B1s[nb][sdst[0]]);
    load16_to_lds(B1base + soff[1] + k1, &B1s[nb][sdst[1]]);
    SBAR();
    asm volatile("s_waitcnt lgkmcnt(0)" ::: "memory");
    SCHED0();
    __builtin_amdgcn_s_setprio(1);
#pragma unroll
    for (int i = 0; i < 4; i++)
#pragma unroll
      for (int j = 0; j < 4; j++)
        acc_g[i][j] = __builtin_amdgcn_mfma_f32_16x16x32_bf16(
            a0[i], bb[j], acc_g[i][j], 0, 0, 0);
    __builtin_amdgcn_s_setprio(0);
    SBAR();

    // -------- P2 --------
#pragma unroll
    for (int i = 0; i < 4; i++) a1[i] = *(const short8*)&Ac[arowE[i] + kx1];
#pragma unroll
    for (int j = 0; j < 4; j++) bb[j] = *(const short8*)&B1c[browE[j] + kx1];
    load16_to_lds(B3base + soff[0] + k1, &B3s[nb][sdst[0]]);
    load16_to_lds(B3base + soff[1] + k1, &B3s[nb][sdst[1]]);
    SBAR();
    asm volatile("s_waitcnt lgkmcnt(0)" ::: "memory");
    SCHED0();
    __builtin_amdgcn_s_setprio(1);
#pragma unroll
    for (int i = 0; i < 4; i++)
#pragma unroll
      for (int j = 0; j < 4; j++)
        acc_g[i][j] = __builtin_amdgcn_mfma_f32_16x16x32_bf16(
            a1[i], bb[j], acc_g[i][j], 0, 0, 0);
    __builtin_amdgcn_s_setprio(0);
    asm volatile("s_waitcnt vmcnt(8)" ::: "memory");  // b3(t) landed
    SBAR();
    SCHED0();  // keep P3 reads below the landing fence

    // -------- P3 --------  (As/B1s[cb] fully consumed -> safe to restage A)
#pragma unroll
    for (int j = 0; j < 4; j++) bb[j] = *(const short8*)&B3c[browE[j] + kx0];
    load16_to_lds(Abase + soff[0] + k2, &As[cb][sdst[0]]);
    load16_to_lds(Abase + soff[1] + k2, &As[cb][sdst[1]]);
    SBAR();
    asm volatile("s_waitcnt lgkmcnt(0)" ::: "memory");
    SCHED0();
    __builtin_amdgcn_s_setprio(1);
#pragma unroll
    for (int i = 0; i < 4; i++)
#pragma unroll
      for (int j = 0; j < 4; j++)
        acc_u[i][j] = __builtin_amdgcn_mfma_f32_16x16x32_bf16(
            a0[i], bb[j], acc_u[i][j], 0, 0, 0);
    __builtin_amdgcn_s_setprio(0);
    SBAR();

    // -------- P4 --------
#pragma unroll
    for (int j = 0; j < 4; j++) bb[j] = *(const short8*)&B3c[browE[j] + kx1];
    load16_to_lds(Abase + soff[2] + k2, &As[cb][sdst[2]]);
    load16_to_lds(Abase + soff[3] + k2, &As[cb][sdst[3]]);
    SBAR();
    asm volatile("s_waitcnt lgkmcnt(0)" ::: "memory");
    SCHED0();
    __builtin_amdgcn_s_setprio(1);
#pragma unroll
    for (int i = 0; i < 4; i++)
#pragma unroll
      for (int j = 0; j < 4; j++)
        acc_u[i][j] = __builtin_amdgcn_mfma_f32_16x16x32_bf16(
            a1[i], bb[j], acc_u[i][j], 0, 0, 0);
    __builtin_amdgcn_s_setprio(0);
    asm volatile("s_waitcnt vmcnt(6)" ::: "memory");  // a(t+1),b1(t+1) landed
    SBAR();
    SCHED0();  // keep next P1 reads below the landing fence
  }

  // epilogue: D col = lane&15, row = quad*4 + reg (m89/m91-verified)
#pragma unroll
  for (int i = 0; i < 4; i++) {
    int row0 = m0 + wm * 64 + i * 16 + q * 4;
#pragma unroll
    for (int j = 0; j < 4; j++) {
      int col = n0 + wn * 64 + j * 16 + r16;
#pragma unroll
      for (int rr = 0; rr < 4; rr++) {
        float gv = acc_g[i][j][rr];
        float uv = acc_u[i][j][rr];
        float sv = gv / (1.f + __expf(-gv)) * uv;
        C[(size_t)(row0 + rr) * N + col] = f2bf(sv);
      }
    }
  }
}

// ---------- GEMM3: C[M,N] = A[M,K] * B[N,K]^T, bf16 in, fp32 out ----------
__global__ __launch_bounds__(256, 2) void gemm_nt_f32_4w(
    const unsigned short* __restrict__ A,  // [M,K] bf16
    const unsigned short* __restrict__ B,  // [N,K] bf16
    float* __restrict__ C,                 // [M,N] fp32
    int M, int N, int K) {
  __shared__ unsigned short As[128 * 64];
  __shared__ unsigned short Bs[128 * 64];

  const int tid = threadIdx.x;
  const int lane = tid & 63;
  const int wave = tid >> 6;
  const int wm = wave >> 1;       // 0..1
  const int wn = wave & 1;        // 0..1
  const int m0 = blockIdx.y * 128, n0 = blockIdx.x * 128;

  int soff[4], sdst[4];
#pragma unroll
  for (int p = 0; p < 4; p++) {
    int u = tid + 256 * p;
    int r = u >> 3;
    int c = ((u & 7) ^ (r & 7)) * 8;
    soff[p] = r * K + c;
    sdst[p] = u * 8;
  }

  const int q = lane >> 4;
  const int r16 = lane & 15;
  const int rx = r16 & 7;

  floatx4 acc[4][4];
#pragma unroll
  for (int i = 0; i < 4; i++)
#pragma unroll
    for (int j = 0; j < 4; j++) acc[i][j] = (floatx4){0.f, 0.f, 0.f, 0.f};

  const unsigned short* Abase = A + (size_t)m0 * K;
  const unsigned short* Bbase = B + (size_t)n0 * K;

  for (int k0 = 0; k0 < K; k0 += 64) {
#pragma unroll
    for (int p = 0; p < 4; p++) {
      load16_to_lds(Abase + soff[p] + k0, &As[sdst[p]]);
      load16_to_lds(Bbase + soff[p] + k0, &Bs[sdst[p]]);
    }
    __syncthreads();

#pragma unroll
    for (int kh = 0; kh < 2; kh++) {
      const int kq = kh * 4 + q;
      short8 a[4], b[4];
#pragma unroll
      for (int t = 0; t < 4; t++) {
        int row = wm * 64 + t * 16 + r16;
        a[t] = *(const short8*)&As[(row * 8 + (kq ^ rx)) * 8];
      }
#pragma unroll
      for (int j = 0; j < 4; j++) {
        int row = wn * 64 + j * 16 + r16;
        b[j] = *(const short8*)&Bs[(row * 8 + (kq ^ rx)) * 8];
      }
#pragma unroll
      for (int i = 0; i < 4; i++)
#pragma unroll
        for (int j = 0; j < 4; j++)
          acc[i][j] = __builtin_amdgcn_mfma_f32_16x16x32_bf16(
              a[i], b[j], acc[i][j], 0, 0, 0);
    }
    __syncthreads();
  }

#pragma unroll
  for (int i = 0; i < 4; i++) {
    int row0 = m0 + wm * 64 + i * 16 + q * 4;
#pragma unroll
    for (int j = 0; j < 4; j++) {
      int col = n0 + wn * 64 + j * 16 + r16;
#pragma unroll
      for (int rr = 0; rr < 4; rr++)
        C[(size_t)(row0 + rr) * N + col] = acc[i][j][rr];
    }
  }
}

// ---------- launch ----------
extern "C" void kernel_launch(void* const* d_in, const int* in_sizes, int n_in,
                              void* d_out, int out_size, void* d_ws, size_t ws_size,
                              hipStream_t stream) {
  const float* x = (const float*)d_in[0];
  const float* w1q = (const float*)d_in[1];
  const float* w1s = (const float*)d_in[2];
  const float* w3q = (const float*)d_in[3];
  const float* w3s = (const float*)d_in[4];
  const float* w2q = (const float*)d_in[5];
  const float* w2s = (const float*)d_in[6];

  const int T = 4096, H = 2048, F = 7168;

  char* ws = (char*)d_ws;
  unsigned short* xb  = (unsigned short*)ws;  ws += (size_t)T * H * 2;   // 16.8 MB
  unsigned short* w1b = (unsigned short*)ws;  ws += (size_t)F * H * 2;   // 29.4 MB
  unsigned short* w3b = (unsigned short*)ws;  ws += (size_t)F * H * 2;   // 29.4 MB
  unsigned short* w2b = (unsigned short*)ws;  ws += (size_t)H * F * 2;   // 29.4 MB
  unsigned short* g   = (unsigned short*)ws;  ws += (size_t)T * F * 2;   // 58.7 MB

  long xn4 = (long)T * H / 4;

  f32_to_bf16_kernel<<<(xn4 + 255) / 256, 256, 0, stream>>>(x, xb, xn4);
  dequant2_kernel<<<dim3(H / 1024, F), 256, 0, stream>>>(
      w1q, w1s, w3q, w3s, w1b, w3b, H, H / 128);
  dequant1_kernel<<<dim3(F / 1024, H), 256, 0, stream>>>(
      w2q, w2s, w2b, F, F / 128);

  // g = silu(x @ w1^T) * (x @ w3^T)   -- 8-phase pipelined, 896 blocks
  dual_gemm_silu_8p<<<dim3((T / 256) * (F / 128)), 512, 0, stream>>>(
      xb, w1b, w3b, g, T, F, H);

  // out = g @ w2^T  (fp32 out)
  gemm_nt_f32_4w<<<dim3(H / 128, T / 128), 256, 0, stream>>>(g, w2b, (float*)d_out, T, H, F);
}